// Round 11
// baseline (259.920 us; speedup 1.0000x reference)
//
#include <hip/hip_runtime.h>
#include <hip/hip_bf16.h>

typedef unsigned short u16;
typedef short short8 __attribute__((ext_vector_type(8)));
typedef float f32x4 __attribute__((ext_vector_type(4)));

// EMBED=256, NH=8, HD=32, NPAIR=16, K_PER_Q=164; levels 128,64,32,16
// compact rows/batch = 16384+4096+1024+256 = 21760
#define ROWS_PER_BATCH 21760
#define TOT_ROWS 43520
#define KV_BLOCKS (TOT_ROWS / 128)   // 340

__device__ __forceinline__ u16 f2bf(float f){
  unsigned u = __builtin_bit_cast(unsigned, f);
  u += 0x7FFFu + ((u >> 16) & 1u);
  return (u16)(u >> 16);
}
__device__ __forceinline__ float bf2f(u16 h){
  return __builtin_bit_cast(float, ((unsigned)h) << 16);
}
__device__ __forceinline__ float bflo(unsigned u){ return __builtin_bit_cast(float, u << 16); }
__device__ __forceinline__ float bfhi(unsigned u){ return __builtin_bit_cast(float, u & 0xFFFF0000u); }
__device__ __forceinline__ unsigned pk2bf(float a, float b){
  __hip_bfloat162 h = __float22bfloat162_rn(make_float2(a, b));
  union { __hip_bfloat162 h2; unsigned u; } cv; cv.h2 = h; return cv.u;
}

// ---------- prep: weight pack (blocks 0..127) + LayerNorm (blocks 128..) ----------
// which 0..2 (wtq/wtk/wtv): MFMA-packed layout
//   packed[((cg*8+kk)*64+lane)*8+j] = W[kk*32+(lane>>4)*8+j][cg*16+(lane&15)]
// which 3: row-major bf16 copy of out_w -> wtor (consumed by attn3's fused
//   out-projection matvec; the MFMA-packed wto is no longer needed).
__global__ __launch_bounds__(256) void prep_kernel(
    const float* __restrict__ qw, const float* __restrict__ kw,
    const float* __restrict__ vw, const float* __restrict__ ow,
    const float* __restrict__ q, const float* __restrict__ nw,
    const float* __restrict__ nb,
    u16* __restrict__ wtq, u16* __restrict__ wtk,
    u16* __restrict__ wtv, u16* __restrict__ wtor, u16* __restrict__ x){
  const int bx = blockIdx.x;
  const int t = threadIdx.x;
  if (bx < 128){
    int e = bx * 256 + t;
    int which = e >> 13;
    int r = e & 8191;
    if (which == 3){
      // row-major bf16 copy: wtor[e8..e8+7] = bf16(out_w[e8..e8+7])
      int e8 = r * 8;
      float4 a0 = *(const float4*)(ow + e8);
      float4 a1 = *(const float4*)(ow + e8 + 4);
      uint4 o = { pk2bf(a0.x, a0.y), pk2bf(a0.z, a0.w),
                  pk2bf(a1.x, a1.y), pk2bf(a1.z, a1.w) };
      *(uint4*)(wtor + e8) = o;
    } else {
      int cg = r >> 9;
      int kk = (r >> 6) & 7;
      int lane = r & 63;
      int quad = lane >> 4, mn = lane & 15;
      const float* s = which == 0 ? qw : which == 1 ? kw : vw;
      u16* d       = which == 0 ? wtq : which == 1 ? wtk : wtv;
      const float* base = s + (kk * 32 + quad * 8) * 256 + cg * 16 + mn;
      float e8[8];
      #pragma unroll
      for (int j = 0; j < 8; ++j) e8[j] = base[j * 256];
      uint4 o = { pk2bf(e8[0], e8[1]), pk2bf(e8[2], e8[3]),
                  pk2bf(e8[4], e8[5]), pk2bf(e8[6], e8[7]) };
      *(uint4*)(d + (size_t)r * 8) = o;
    }
  } else {
    const int row = (bx - 128) * 4 + (t >> 6);
    const int lane = t & 63;
    const float4 v = *(const float4*)(q + (size_t)row * 256 + lane * 4);
    float s1 = v.x + v.y + v.z + v.w;
    float s2 = v.x*v.x + v.y*v.y + v.z*v.z + v.w*v.w;
    #pragma unroll
    for (int o = 32; o > 0; o >>= 1){
      s1 += __shfl_xor(s1, o);
      s2 += __shfl_xor(s2, o);
    }
    float mu = s1 * (1.0f / 256.0f);
    float var = s2 * (1.0f / 256.0f) - mu * mu;
    float rs = rsqrtf(var + 1e-5f);
    const float4 wv = *(const float4*)(nw + lane * 4);
    const float4 bv = *(const float4*)(nb + lane * 4);
    float o0 = (v.x - mu) * rs * wv.x + bv.x;
    float o1 = (v.y - mu) * rs * wv.y + bv.y;
    float o2 = (v.z - mu) * rs * wv.z + bv.z;
    float o3 = (v.w - mu) * rs * wv.w + bv.w;
    uint2 pk = { pk2bf(o0, o1), pk2bf(o2, o3) };
    *(uint2*)(x + (size_t)row * 256 + lane * 4) = pk;
  }
}

// ---------- merged: K+V projection (blocks 0..339) + Q projection (340..467) ----------
// qproj: 128 merged blocks x step-loop{0,1} x (t>>8) cover ALL 512 old 256-thr
// gemm blocks (r10 BUG FIX: its grid expression covered only 256 of 512 ->
// qraw cols 128..255 were never written; error hid under the bf16-noise absmax
// because |V| ~ 0.02). Grid 468 <= 512 resident slots (75KB LDS -> 2 blocks/CU)
// -> full residency, no dispatch tail.
__global__ __launch_bounds__(512, 4) void kv_qproj(const float* __restrict__ fm,
        const u16* __restrict__ wtkp, const u16* __restrict__ wtvp,
        const u16* __restrict__ wtqp, const u16* __restrict__ xbf,
        const float* __restrict__ rope,
        u16* __restrict__ krot, u16* __restrict__ vmap,
        float* __restrict__ qraw){
  __shared__ u16 bstage[32 * 512];        // 32 KB: one cs2 group (32 tiles)
  __shared__ float slab[8][16][66];       // per-wave transpose slab
  __shared__ unsigned sh_cs[8][16][16];   // per-wave cos/sin

  const int t = threadIdx.x;

  if (blockIdx.x >= KV_BLOCKS){
    // ---- q-proj: qraw[2048][256] = xbf @ wtq ; 4 old blocks per 512-thr block ----
    #pragma unroll 1
    for (int step = 0; step < 2; ++step){
      const int ob = (blockIdx.x - KV_BLOCKS) * 4 + step * 2 + (t >> 8); // [0,512)
      const int bx = ob & 127, by = ob >> 7;
      const int tt = t & 255;
      const int wv = tt >> 6;
      const int lane = tt & 63;
      const int mn = lane & 15;
      const int quad = lane >> 4;
      const int cg = by * 4 + wv;
      const int row0 = bx * 16;

      short8 af[8];
      {
        const u16* arow = xbf + (size_t)(row0 + mn) * 256 + quad * 8;
        #pragma unroll
        for (int kk = 0; kk < 8; ++kk)
          af[kk] = *(const short8*)(arow + kk * 32);
      }
      const u16* wb = wtqp + (size_t)((cg * 8) * 64 + lane) * 8;
      short8 bc = *(const short8*)wb;
      f32x4 acc = (f32x4){0.f, 0.f, 0.f, 0.f};
      #pragma unroll
      for (int kk = 0; kk < 8; ++kk){
        short8 bn;
        if (kk < 7) bn = *(const short8*)(wb + (size_t)(kk + 1) * 64 * 8);
        acc = __builtin_amdgcn_mfma_f32_16x16x32_bf16(af[kk], bc, acc, 0, 0, 0);
        bc = bn;
      }
      const int col = cg * 16 + mn;
      #pragma unroll
      for (int r = 0; r < 4; ++r)
        qraw[(size_t)(row0 + quad * 4 + r) * 256 + col] = acc[r];
    }
    return;
  }

  // ---- kv path (identical compute to r9) ----
  const int w = t >> 6;
  const int lane = t & 63;
  const int row0 = blockIdx.x * 128 + w * 16;   // this wave's 16 rows

  const int b = row0 / ROWS_PER_BATCH;
  const int rr = row0 - b * ROWS_PER_BATCH;
  int l, loff;
  if (rr < 16384)      { l = 0; loff = 0; }
  else if (rr < 20480) { l = 1; loff = 16384; }
  else if (rr < 21504) { l = 2; loff = 20480; }
  else                 { l = 3; loff = 21504; }
  const int logW = 7 - l;
  const int Wm1 = (128 >> l) - 1;
  const int cell0 = rr - loff;
  const float* fmbase = fm + (size_t)(b * 4 + l) * (128 * 128 * 256);

  const int mn = lane & 15;
  const int quad = lane >> 4;

  // A fragments straight from global (fp32 -> bf16 in regs), per wave
  short8 af[8];
  {
    int cell = cell0 + mn;
    int y = cell >> logW, x = cell & Wm1;
    const float* arow = fmbase + (((y << 7) + x) << 8) + quad * 8;
    #pragma unroll
    for (int kk = 0; kk < 8; ++kk){
      float4 a0 = *(const float4*)(arow + kk * 32);
      float4 a1 = *(const float4*)(arow + kk * 32 + 4);
      union { short8 s; uint4 u; } cv;
      cv.u = (uint4){ pk2bf(a0.x, a0.y), pk2bf(a0.z, a0.w),
                      pk2bf(a1.x, a1.y), pk2bf(a1.z, a1.w) };
      af[kk] = cv.s;
    }
  }

  // cos/sin table: per wave, 16 rows x 16 pairs
  #pragma unroll
  for (int i = 0; i < 4; ++i){
    int id = i * 64 + lane;
    int lr = id >> 4, p = id & 15;
    int cell = cell0 + lr;
    int i0 = cell >> logW;
    int i1 = cell & Wm1;
    float fs = (float)(1 << l);
    float kx = ((float)i0 + 0.5f) * fs;
    float ky = ((float)i1 + 0.5f) * fs;
    float ang = kx * rope[p] + ky * rope[16 + p] + (float)l * rope[32 + p];
    sh_cs[w][lr][p] = pk2bf(__cosf(ang), __sinf(ang));
  }

  for (int m = 0; m < 2; ++m){
    const u16* wtp = m ? wtvp : wtkp;
    u16* outp = m ? vmap : krot;
    for (int cs2 = 0; cs2 < 4; ++cs2){
      __syncthreads();   // previous group fully consumed before overwrite
      // cooperative stage: 32KB = 512 thr x 4 x 16B
      const u16* src = wtp + (size_t)cs2 * 16384;
      #pragma unroll
      for (int i = 0; i < 4; ++i)
        *(uint4*)(bstage + ((size_t)(i * 512 + t)) * 8) =
            *(const uint4*)(src + ((size_t)(i * 512 + t)) * 8);
      __syncthreads();   // stage visible to all waves

      f32x4 acc[4];
      #pragma unroll
      for (int i = 0; i < 4; ++i) acc[i] = (f32x4){0.f, 0.f, 0.f, 0.f};
      #pragma unroll
      for (int kk = 0; kk < 8; ++kk){
        #pragma unroll
        for (int tl = 0; tl < 4; ++tl){
          short8 bc = *(const short8*)(bstage + ((tl * 8 + kk) * 64 + lane) * 8);
          acc[tl] = __builtin_amdgcn_mfma_f32_16x16x32_bf16(af[kk], bc, acc[tl], 0, 0, 0);
        }
      }

      // wave-local epilogue: slab transpose -> (RoPE) -> coalesced bf16 store
      #pragma unroll
      for (int tl = 0; tl < 4; ++tl)
        #pragma unroll
        for (int r = 0; r < 4; ++r)
          slab[w][quad * 4 + r][tl * 16 + mn] = acc[tl][r];
      #pragma unroll
      for (int i = 0; i < 8; ++i){
        int pi = i * 64 + lane;
        int row = pi >> 5;
        int pl = pi & 31;
        float2 kv2 = *(const float2*)&slab[w][row][pl * 2];
        unsigned o;
        if (m == 0){
          unsigned csn = sh_cs[w][row][pl & 15];
          float c = bflo(csn), s = bfhi(csn);
          o = pk2bf(kv2.x * c - kv2.y * s, kv2.x * s + kv2.y * c);
        } else {
          o = pk2bf(kv2.x, kv2.y);
        }
        *(unsigned*)(outp + (size_t)(row0 + row) * 256 + cs2 * 64 + pl * 2) = o;
      }
    }
  }
}

// ---------- attention core + fused out-projection: ONE WAVE PER QUERY ----------
// grid n_q/4 x 256 thr. All LDS wave-private; intra-wave RAW ordered by lgkmcnt
// (no barriers). v5: after PV, the normalized O row is stashed in LDS (f32, no
// bf16 round-trip) and the SAME wave computes out[qi] = O @ wtor + residual via
// a 2-rows-per-iter matvec (PV-style shfl_xor(32) merge). This removes the
// final gemm_xw launch+gap, and the dense matvec overlaps other waves' gather
// stalls (attn pipes were ~90% idle, r6 PMC).
__global__ __launch_bounds__(256) void attn3(
    const float* __restrict__ qraw, const float* __restrict__ qsp,
    const float* __restrict__ rope, const int* __restrict__ qbo, int nbo,
    const u16* __restrict__ krot, const u16* __restrict__ vmap,
    const u16* __restrict__ wtor, const float* __restrict__ resid,
    float* __restrict__ out){
  __shared__ float sh_q[4][8][33];
  __shared__ float sh_lg[4][168][8];
  __shared__ int   sh_row[4][168];
  __shared__ float sh_inv[4][8];
  __shared__ float sh_o[4][256];
  const int t = threadIdx.x;
  const int w = t >> 6;
  const int lane = t & 63;
  const int qi = blockIdx.x * 4 + w;

  int bidx = 0;
  for (int j = 1; j < nbo; ++j) if (qi >= qbo[j]) bidx = j;
  const float p0 = qsp[qi * 2 + 0];
  const float p1 = qsp[qi * 2 + 1];

  // q RoPE (1/sqrt(32) folded); 4 iters x 64 lanes cover 256 dims
  #pragma unroll
  for (int it = 0; it < 4; ++it){
    int d = it * 64 + lane;
    float qv = qraw[(size_t)qi * 256 + d];
    int p = (d & 31) >> 1;
    float ang = p0 * rope[p] + p1 * rope[16 + p];
    float c = __cosf(ang), s = __sinf(ang);
    float partner = __shfl_xor(qv, 1);
    float val = (d & 1) ? (partner * s + qv * c) : (qv * c - partner * s);
    sh_q[w][d >> 5][d & 31] = val * 0.17677669529663687f;
  }

  // key rows + validity
  #pragma unroll
  for (int it = 0; it < 3; ++it){
    int kk = it * 64 + lane;
    if (kk < 164){
      int l, dy, dx, loff;
      if (kk < 9)       { l = 0; int j = kk;      dy = j / 3 - 1; dx = j % 3 - 1; loff = 0; }
      else if (kk < 34) { l = 1; int j = kk - 9;  dy = j / 5 - 2; dx = j % 5 - 2; loff = 16384; }
      else if (kk < 83) { l = 2; int j = kk - 34; dy = j / 7 - 3; dx = j % 7 - 3; loff = 20480; }
      else              { l = 3; int j = kk - 83; dy = j / 9 - 4; dx = j % 9 - 4; loff = 21504; }
      float sc = 1.0f / (float)(1 << l);
      int i0 = (int)floorf(p0 * sc) + dy;
      int i1 = (int)floorf(p1 * sc) + dx;
      int W = 128 >> l;
      sh_row[w][kk] = (i0 < 0 || i0 >= W || i1 < 0 || i1 >= W)
                ? -1 : bidx * ROWS_PER_BATCH + loff + (i0 << (7 - l)) + i1;
    }
  }

  // logits: lane = (ksub, h); wave reads 8 contiguous 512B K rows per pass
  const int h = lane & 7;
  const int ksub = lane >> 3;
  float qreg[32];
  #pragma unroll
  for (int j = 0; j < 32; ++j) qreg[j] = sh_q[w][h][j];
  for (int pass = 0; pass < 21; ++pass){
    int kk = pass * 8 + ksub;
    if (kk < 164){
      int row = sh_row[w][kk];
      float lg = -1e9f;
      if (row >= 0){
        const uint4* kp = (const uint4*)(krot + (size_t)row * 256 + h * 32);
        uint4 A0 = kp[0], A1 = kp[1], A2 = kp[2], A3 = kp[3];
        unsigned uu[16];
        uu[0]=A0.x; uu[1]=A0.y; uu[2]=A0.z; uu[3]=A0.w;
        uu[4]=A1.x; uu[5]=A1.y; uu[6]=A1.z; uu[7]=A1.w;
        uu[8]=A2.x; uu[9]=A2.y; uu[10]=A2.z; uu[11]=A2.w;
        uu[12]=A3.x; uu[13]=A3.y; uu[14]=A3.z; uu[15]=A3.w;
        // 4 independent partial sums -> dependent-FMA chain 8 deep, not 32
        float s0 = 0.f, s1 = 0.f, s2 = 0.f, s3 = 0.f;
        #pragma unroll
        for (int j = 0; j < 4; ++j){
          s0 += qreg[2*j]      * bflo(uu[j])      + qreg[2*j+1]  * bfhi(uu[j]);
          s1 += qreg[2*j+8]    * bflo(uu[j+4])    + qreg[2*j+9]  * bfhi(uu[j+4]);
          s2 += qreg[2*j+16]   * bflo(uu[j+8])    + qreg[2*j+17] * bfhi(uu[j+8]);
          s3 += qreg[2*j+24]   * bflo(uu[j+12])   + qreg[2*j+25] * bfhi(uu[j+12]);
        }
        lg = (s0 + s1) + (s2 + s3);
      }
      sh_lg[w][kk][h] = lg;
    }
  }

  // softmax: 8 lanes per head (xor 8/16/32 butterflies preserve h)
  float mx = -1e30f;
  for (int kk = ksub; kk < 164; kk += 8) mx = fmaxf(mx, sh_lg[w][kk][h]);
  #pragma unroll
  for (int o = 8; o < 64; o <<= 1) mx = fmaxf(mx, __shfl_xor(mx, o));
  float ssum = 0.f;
  for (int kk = ksub; kk < 164; kk += 8){
    float e = __expf(sh_lg[w][kk][h] - mx);    // invalid keys -> exactly 0
    sh_lg[w][kk][h] = e;
    ssum += e;
  }
  #pragma unroll
  for (int o = 8; o < 64; o <<= 1) ssum += __shfl_xor(ssum, o);
  if (ksub == 0) sh_inv[w][h] = 1.0f / ssum;

  // PV: 2 keys/iter; lane = (parity, 8-dim group); 16B coalesced V loads
  const int c = lane & 31;        // dims c*8 .. c*8+7
  const int p2 = lane >> 5;       // key parity
  const int hh = c >> 2;          // head of this dim group
  float a[8] = {0.f,0.f,0.f,0.f,0.f,0.f,0.f,0.f};
  #pragma unroll 4
  for (int ii = 0; ii < 82; ++ii){
    int kk = ii * 2 + p2;
    int row = sh_row[w][kk];
    int rc = row < 0 ? 0 : row;
    uint4 vv = *(const uint4*)(vmap + (size_t)rc * 256 + c * 8);
    float e = sh_lg[w][kk][hh];   // invalid -> 0
    a[0] += e * bflo(vv.x); a[1] += e * bfhi(vv.x);
    a[2] += e * bflo(vv.y); a[3] += e * bfhi(vv.y);
    a[4] += e * bflo(vv.z); a[5] += e * bfhi(vv.z);
    a[6] += e * bflo(vv.w); a[7] += e * bfhi(vv.w);
  }
  #pragma unroll
  for (int j = 0; j < 8; ++j) a[j] += __shfl_xor(a[j], 32);
  if (p2 == 0){
    float inv = sh_inv[w][hh];
    #pragma unroll
    for (int j = 0; j < 8; ++j) sh_o[w][c * 8 + j] = a[j] * inv;  // f32, no bf16 trip
  }

  // fused out-projection: out[qi][:] = sh_o[w] @ wtor + resid[qi][:]
  // lanes 0-31 take even k rows, 32-63 odd; lane covers cols (lane&31)*8..+7
  {
    const int kpar = lane >> 5;
    float b2[8] = {0.f,0.f,0.f,0.f,0.f,0.f,0.f,0.f};
    #pragma unroll 4
    for (int ii = 0; ii < 128; ++ii){
      int k = ii * 2 + kpar;
      float ak = sh_o[w][k];                 // 2-address LDS broadcast
      uint4 ww = *(const uint4*)(wtor + (size_t)k * 256 + c * 8);
      b2[0] += ak * bflo(ww.x); b2[1] += ak * bfhi(ww.x);
      b2[2] += ak * bflo(ww.y); b2[3] += ak * bfhi(ww.y);
      b2[4] += ak * bflo(ww.z); b2[5] += ak * bfhi(ww.z);
      b2[6] += ak * bflo(ww.w); b2[7] += ak * bfhi(ww.w);
    }
    #pragma unroll
    for (int j = 0; j < 8; ++j) b2[j] += __shfl_xor(b2[j], 32);
    if (kpar == 0){
      const float* rp = resid + (size_t)qi * 256 + c * 8;
      float4 r0 = *(const float4*)rp;
      float4 r1 = *(const float4*)(rp + 4);
      float* op = out + (size_t)qi * 256 + c * 8;
      *(float4*)op       = (float4){b2[0]+r0.x, b2[1]+r0.y, b2[2]+r0.z, b2[3]+r0.w};
      *(float4*)(op + 4) = (float4){b2[4]+r1.x, b2[5]+r1.y, b2[6]+r1.z, b2[7]+r1.w};
    }
  }
}

extern "C" void kernel_launch(void* const* d_in, const int* in_sizes, int n_in,
                              void* d_out, int out_size, void* d_ws, size_t ws_size,
                              hipStream_t stream) {
  (void)n_in; (void)out_size; (void)ws_size;
  const float* query  = (const float*)d_in[0];
  const float* qsp    = (const float*)d_in[1];
  const float* fm     = (const float*)d_in[2];
  const float* norm_w = (const float*)d_in[3];
  const float* norm_b = (const float*)d_in[4];
  const float* q_w    = (const float*)d_in[5];
  const float* k_w    = (const float*)d_in[6];
  const float* v_w    = (const float*)d_in[7];
  const float* out_w  = (const float*)d_in[8];
  const float* rope   = (const float*)d_in[9];
  const int*   qbo    = (const int*)d_in[10];
  float* out = (float*)d_out;
  const int n_q = in_sizes[0] / 256;
  const int nbo = in_sizes[10];

  char* p = (char*)d_ws;
  u16* krot = (u16*)p;                       p += (size_t)TOT_ROWS * 256 * 2;
  u16* vmap = (u16*)p;                       p += (size_t)TOT_ROWS * 256 * 2;
  float* qraw = (float*)p;                   p += (size_t)n_q * 256 * 4;
  u16* xbf = (u16*)p;                        p += (size_t)n_q * 256 * 2;
  u16* wtq = (u16*)p;                        p += 65536 * 2;
  u16* wtk = (u16*)p;                        p += 65536 * 2;
  u16* wtv = (u16*)p;                        p += 65536 * 2;
  u16* wtor = (u16*)p;

  hipLaunchKernelGGL(prep_kernel, dim3(128 + n_q / 4), dim3(256), 0, stream,
                     q_w, k_w, v_w, out_w, query, norm_w, norm_b,
                     wtq, wtk, wtv, wtor, xbf);
  hipLaunchKernelGGL(kv_qproj, dim3(KV_BLOCKS + n_q / 16), dim3(512), 0, stream,
                     fm, wtk, wtv, wtq, xbf, rope, krot, vmap, qraw);
  hipLaunchKernelGGL(attn3, dim3(n_q / 4), dim3(256), 0, stream,
                     qraw, qsp, rope, qbo, nbo, krot, vmap, wtor, query, out);
}

// Round 12
// 252.392 us; speedup vs baseline: 1.0298x; 1.0298x over previous
//
#include <hip/hip_runtime.h>
#include <hip/hip_bf16.h>

typedef unsigned short u16;
typedef short short8 __attribute__((ext_vector_type(8)));
typedef float f32x4 __attribute__((ext_vector_type(4)));

// EMBED=256, NH=8, HD=32, NPAIR=16, K_PER_Q=164; levels 128,64,32,16
// compact rows/batch = 16384+4096+1024+256 = 21760
#define ROWS_PER_BATCH 21760
#define TOT_ROWS 43520
#define KV_BLOCKS (TOT_ROWS / 128)   // 340

__device__ __forceinline__ u16 f2bf(float f){
  unsigned u = __builtin_bit_cast(unsigned, f);
  u += 0x7FFFu + ((u >> 16) & 1u);
  return (u16)(u >> 16);
}
__device__ __forceinline__ float bf2f(u16 h){
  return __builtin_bit_cast(float, ((unsigned)h) << 16);
}
__device__ __forceinline__ float bflo(unsigned u){ return __builtin_bit_cast(float, u << 16); }
__device__ __forceinline__ float bfhi(unsigned u){ return __builtin_bit_cast(float, u & 0xFFFF0000u); }
__device__ __forceinline__ unsigned pk2bf(float a, float b){
  __hip_bfloat162 h = __float22bfloat162_rn(make_float2(a, b));
  union { __hip_bfloat162 h2; unsigned u; } cv; cv.h2 = h; return cv.u;
}

// ---------- prep: weight pack (blocks 0..127) + LayerNorm (blocks 128..) ----------
// packed[((cg*8 + kk)*64 + lane)*8 + j] = W[kk*32 + (lane>>4)*8 + j][cg*16 + (lane&15)]
__global__ __launch_bounds__(256) void prep_kernel(
    const float* __restrict__ qw, const float* __restrict__ kw,
    const float* __restrict__ vw, const float* __restrict__ ow,
    const float* __restrict__ q, const float* __restrict__ nw,
    const float* __restrict__ nb,
    u16* __restrict__ wtq, u16* __restrict__ wtk,
    u16* __restrict__ wtv, u16* __restrict__ wto, u16* __restrict__ x){
  const int bx = blockIdx.x;
  const int t = threadIdx.x;
  if (bx < 128){
    int e = bx * 256 + t;
    int which = e >> 13;
    int r = e & 8191;
    int cg = r >> 9;
    int kk = (r >> 6) & 7;
    int lane = r & 63;
    int quad = lane >> 4, mn = lane & 15;
    const float* s = which == 0 ? qw : which == 1 ? kw : which == 2 ? vw : ow;
    u16* d       = which == 0 ? wtq : which == 1 ? wtk : which == 2 ? wtv : wto;
    const float* base = s + (kk * 32 + quad * 8) * 256 + cg * 16 + mn;
    float e8[8];
    #pragma unroll
    for (int j = 0; j < 8; ++j) e8[j] = base[j * 256];
    uint4 o = { pk2bf(e8[0], e8[1]), pk2bf(e8[2], e8[3]),
                pk2bf(e8[4], e8[5]), pk2bf(e8[6], e8[7]) };
    *(uint4*)(d + (size_t)r * 8) = o;
  } else {
    const int row = (bx - 128) * 4 + (t >> 6);
    const int lane = t & 63;
    const float4 v = *(const float4*)(q + (size_t)row * 256 + lane * 4);
    float s1 = v.x + v.y + v.z + v.w;
    float s2 = v.x*v.x + v.y*v.y + v.z*v.z + v.w*v.w;
    #pragma unroll
    for (int o = 32; o > 0; o >>= 1){
      s1 += __shfl_xor(s1, o);
      s2 += __shfl_xor(s2, o);
    }
    float mu = s1 * (1.0f / 256.0f);
    float var = s2 * (1.0f / 256.0f) - mu * mu;
    float rs = rsqrtf(var + 1e-5f);
    const float4 wv = *(const float4*)(nw + lane * 4);
    const float4 bv = *(const float4*)(nb + lane * 4);
    float o0 = (v.x - mu) * rs * wv.x + bv.x;
    float o1 = (v.y - mu) * rs * wv.y + bv.y;
    float o2 = (v.z - mu) * rs * wv.z + bv.z;
    float o3 = (v.w - mu) * rs * wv.w + bv.w;
    uint2 pk = { pk2bf(o0, o1), pk2bf(o2, o3) };
    *(uint2*)(x + (size_t)row * 256 + lane * 4) = pk;
  }
}

// ---------- merged: K+V projection (blocks 0..339) + Q projection (340..467) ----------
// qproj: 128 merged blocks x step-loop{0,1} x (t>>8) cover ALL 512 old 256-thr
// gemm blocks (r10's grid covered only 256 -> half of qraw unwritten; fixed r11).
// Grid 468 <= 512 resident slots (75KB LDS -> 2 blocks/CU) -> full residency.
// NOTE r11 lesson: do NOT fuse out-proj into attn3 as a per-wave matvec — it
// re-reads 128KB of weights per wave (262 MB total, the r6 trap). gemm_xw's
// MFMA amortizes weights over 16 rows -> 16 MB.
__global__ __launch_bounds__(512, 4) void kv_qproj(const float* __restrict__ fm,
        const u16* __restrict__ wtkp, const u16* __restrict__ wtvp,
        const u16* __restrict__ wtqp, const u16* __restrict__ xbf,
        const float* __restrict__ rope,
        u16* __restrict__ krot, u16* __restrict__ vmap,
        float* __restrict__ qraw){
  __shared__ u16 bstage[32 * 512];        // 32 KB: one cs2 group (32 tiles)
  __shared__ float slab[8][16][66];       // per-wave transpose slab
  __shared__ unsigned sh_cs[8][16][16];   // per-wave cos/sin

  const int t = threadIdx.x;

  if (blockIdx.x >= KV_BLOCKS){
    // ---- q-proj: qraw[2048][256] = xbf @ wtq ; 4 old blocks per 512-thr block ----
    #pragma unroll 1
    for (int step = 0; step < 2; ++step){
      const int ob = (blockIdx.x - KV_BLOCKS) * 4 + step * 2 + (t >> 8); // [0,512)
      const int bx = ob & 127, by = ob >> 7;
      const int tt = t & 255;
      const int wv = tt >> 6;
      const int lane = tt & 63;
      const int mn = lane & 15;
      const int quad = lane >> 4;
      const int cg = by * 4 + wv;
      const int row0 = bx * 16;

      short8 af[8];
      {
        const u16* arow = xbf + (size_t)(row0 + mn) * 256 + quad * 8;
        #pragma unroll
        for (int kk = 0; kk < 8; ++kk)
          af[kk] = *(const short8*)(arow + kk * 32);
      }
      const u16* wb = wtqp + (size_t)((cg * 8) * 64 + lane) * 8;
      short8 bc = *(const short8*)wb;
      f32x4 acc = (f32x4){0.f, 0.f, 0.f, 0.f};
      #pragma unroll
      for (int kk = 0; kk < 8; ++kk){
        short8 bn;
        if (kk < 7) bn = *(const short8*)(wb + (size_t)(kk + 1) * 64 * 8);
        acc = __builtin_amdgcn_mfma_f32_16x16x32_bf16(af[kk], bc, acc, 0, 0, 0);
        bc = bn;
      }
      const int col = cg * 16 + mn;
      #pragma unroll
      for (int r = 0; r < 4; ++r)
        qraw[(size_t)(row0 + quad * 4 + r) * 256 + col] = acc[r];
    }
    return;
  }

  // ---- kv path (identical compute to r9) ----
  const int w = t >> 6;
  const int lane = t & 63;
  const int row0 = blockIdx.x * 128 + w * 16;   // this wave's 16 rows

  const int b = row0 / ROWS_PER_BATCH;
  const int rr = row0 - b * ROWS_PER_BATCH;
  int l, loff;
  if (rr < 16384)      { l = 0; loff = 0; }
  else if (rr < 20480) { l = 1; loff = 16384; }
  else if (rr < 21504) { l = 2; loff = 20480; }
  else                 { l = 3; loff = 21504; }
  const int logW = 7 - l;
  const int Wm1 = (128 >> l) - 1;
  const int cell0 = rr - loff;
  const float* fmbase = fm + (size_t)(b * 4 + l) * (128 * 128 * 256);

  const int mn = lane & 15;
  const int quad = lane >> 4;

  // A fragments straight from global (fp32 -> bf16 in regs), per wave
  short8 af[8];
  {
    int cell = cell0 + mn;
    int y = cell >> logW, x = cell & Wm1;
    const float* arow = fmbase + (((y << 7) + x) << 8) + quad * 8;
    #pragma unroll
    for (int kk = 0; kk < 8; ++kk){
      float4 a0 = *(const float4*)(arow + kk * 32);
      float4 a1 = *(const float4*)(arow + kk * 32 + 4);
      union { short8 s; uint4 u; } cv;
      cv.u = (uint4){ pk2bf(a0.x, a0.y), pk2bf(a0.z, a0.w),
                      pk2bf(a1.x, a1.y), pk2bf(a1.z, a1.w) };
      af[kk] = cv.s;
    }
  }

  // cos/sin table: per wave, 16 rows x 16 pairs
  #pragma unroll
  for (int i = 0; i < 4; ++i){
    int id = i * 64 + lane;
    int lr = id >> 4, p = id & 15;
    int cell = cell0 + lr;
    int i0 = cell >> logW;
    int i1 = cell & Wm1;
    float fs = (float)(1 << l);
    float kx = ((float)i0 + 0.5f) * fs;
    float ky = ((float)i1 + 0.5f) * fs;
    float ang = kx * rope[p] + ky * rope[16 + p] + (float)l * rope[32 + p];
    sh_cs[w][lr][p] = pk2bf(__cosf(ang), __sinf(ang));
  }

  for (int m = 0; m < 2; ++m){
    const u16* wtp = m ? wtvp : wtkp;
    u16* outp = m ? vmap : krot;
    for (int cs2 = 0; cs2 < 4; ++cs2){
      __syncthreads();   // previous group fully consumed before overwrite
      // cooperative stage: 32KB = 512 thr x 4 x 16B
      const u16* src = wtp + (size_t)cs2 * 16384;
      #pragma unroll
      for (int i = 0; i < 4; ++i)
        *(uint4*)(bstage + ((size_t)(i * 512 + t)) * 8) =
            *(const uint4*)(src + ((size_t)(i * 512 + t)) * 8);
      __syncthreads();   // stage visible to all waves

      f32x4 acc[4];
      #pragma unroll
      for (int i = 0; i < 4; ++i) acc[i] = (f32x4){0.f, 0.f, 0.f, 0.f};
      #pragma unroll
      for (int kk = 0; kk < 8; ++kk){
        #pragma unroll
        for (int tl = 0; tl < 4; ++tl){
          short8 bc = *(const short8*)(bstage + ((tl * 8 + kk) * 64 + lane) * 8);
          acc[tl] = __builtin_amdgcn_mfma_f32_16x16x32_bf16(af[kk], bc, acc[tl], 0, 0, 0);
        }
      }

      // wave-local epilogue: slab transpose -> (RoPE) -> coalesced bf16 store
      #pragma unroll
      for (int tl = 0; tl < 4; ++tl)
        #pragma unroll
        for (int r = 0; r < 4; ++r)
          slab[w][quad * 4 + r][tl * 16 + mn] = acc[tl][r];
      #pragma unroll
      for (int i = 0; i < 8; ++i){
        int pi = i * 64 + lane;
        int row = pi >> 5;
        int pl = pi & 31;
        float2 kv2 = *(const float2*)&slab[w][row][pl * 2];
        unsigned o;
        if (m == 0){
          unsigned csn = sh_cs[w][row][pl & 15];
          float c = bflo(csn), s = bfhi(csn);
          o = pk2bf(kv2.x * c - kv2.y * s, kv2.x * s + kv2.y * c);
        } else {
          o = pk2bf(kv2.x, kv2.y);
        }
        *(unsigned*)(outp + (size_t)(row0 + row) * 256 + cs2 * 64 + pl * 2) = o;
      }
    }
  }
}

// ---------- barrier-free MFMA GEMM: out[M][256] = A(bf16) @ WT (+resid) ----------
__global__ __launch_bounds__(256) void gemm_xw(const u16* __restrict__ A,
        const u16* __restrict__ wt, const float* __restrict__ resid,
        float* __restrict__ out){
  const int t = threadIdx.x;
  const int row0 = blockIdx.x * 16;
  const int wv = t >> 6;
  const int lane = t & 63;
  const int mn = lane & 15;
  const int quad = lane >> 4;
  const int cg = blockIdx.y * 4 + wv;

  short8 af[8];
  {
    const u16* arow = A + (size_t)(row0 + mn) * 256 + quad * 8;
    #pragma unroll
    for (int kk = 0; kk < 8; ++kk)
      af[kk] = *(const short8*)(arow + kk * 32);
  }
  const u16* wb = wt + (size_t)((cg * 8) * 64 + lane) * 8;
  short8 bc = *(const short8*)wb;
  f32x4 acc = (f32x4){0.f, 0.f, 0.f, 0.f};
  #pragma unroll
  for (int kk = 0; kk < 8; ++kk){
    short8 bn;
    if (kk < 7) bn = *(const short8*)(wb + (size_t)(kk + 1) * 64 * 8);
    acc = __builtin_amdgcn_mfma_f32_16x16x32_bf16(af[kk], bc, acc, 0, 0, 0);
    bc = bn;
  }
  const int col = cg * 16 + mn;
  #pragma unroll
  for (int r = 0; r < 4; ++r){
    int row = row0 + quad * 4 + r;
    float val = acc[r];
    if (resid) val += resid[(size_t)row * 256 + col];
    out[(size_t)row * 256 + col] = val;
  }
}

// ---------- attention core: ONE WAVE PER QUERY, zero barriers ----------
// grid n_q/4 x 256 thr. All LDS is wave-private; intra-wave RAW ordered by lgkmcnt.
// (r6 measurement: ~30 us cold; gathers ~344 MB vs L3 BW -> at its BW floor.)
__global__ __launch_bounds__(256) void attn3(
    const float* __restrict__ qraw, const float* __restrict__ qsp,
    const float* __restrict__ rope, const int* __restrict__ qbo, int nbo,
    const u16* __restrict__ krot, const u16* __restrict__ vmap,
    u16* __restrict__ ao){
  __shared__ float sh_q[4][8][33];
  __shared__ float sh_lg[4][168][8];
  __shared__ int   sh_row[4][168];
  __shared__ float sh_inv[4][8];
  const int t = threadIdx.x;
  const int w = t >> 6;
  const int lane = t & 63;
  const int qi = blockIdx.x * 4 + w;

  int bidx = 0;
  for (int j = 1; j < nbo; ++j) if (qi >= qbo[j]) bidx = j;
  const float p0 = qsp[qi * 2 + 0];
  const float p1 = qsp[qi * 2 + 1];

  // q RoPE (1/sqrt(32) folded); 4 iters x 64 lanes cover 256 dims
  #pragma unroll
  for (int it = 0; it < 4; ++it){
    int d = it * 64 + lane;
    float qv = qraw[(size_t)qi * 256 + d];
    int p = (d & 31) >> 1;
    float ang = p0 * rope[p] + p1 * rope[16 + p];
    float c = __cosf(ang), s = __sinf(ang);
    float partner = __shfl_xor(qv, 1);
    float val = (d & 1) ? (partner * s + qv * c) : (qv * c - partner * s);
    sh_q[w][d >> 5][d & 31] = val * 0.17677669529663687f;
  }

  // key rows + validity
  #pragma unroll
  for (int it = 0; it < 3; ++it){
    int kk = it * 64 + lane;
    if (kk < 164){
      int l, dy, dx, loff;
      if (kk < 9)       { l = 0; int j = kk;      dy = j / 3 - 1; dx = j % 3 - 1; loff = 0; }
      else if (kk < 34) { l = 1; int j = kk - 9;  dy = j / 5 - 2; dx = j % 5 - 2; loff = 16384; }
      else if (kk < 83) { l = 2; int j = kk - 34; dy = j / 7 - 3; dx = j % 7 - 3; loff = 20480; }
      else              { l = 3; int j = kk - 83; dy = j / 9 - 4; dx = j % 9 - 4; loff = 21504; }
      float sc = 1.0f / (float)(1 << l);
      int i0 = (int)floorf(p0 * sc) + dy;
      int i1 = (int)floorf(p1 * sc) + dx;
      int W = 128 >> l;
      sh_row[w][kk] = (i0 < 0 || i0 >= W || i1 < 0 || i1 >= W)
                ? -1 : bidx * ROWS_PER_BATCH + loff + (i0 << (7 - l)) + i1;
    }
  }

  // logits: lane = (ksub, h); wave reads 8 contiguous 512B K rows per pass
  const int h = lane & 7;
  const int ksub = lane >> 3;
  float qreg[32];
  #pragma unroll
  for (int j = 0; j < 32; ++j) qreg[j] = sh_q[w][h][j];
  for (int pass = 0; pass < 21; ++pass){
    int kk = pass * 8 + ksub;
    if (kk < 164){
      int row = sh_row[w][kk];
      float lg = -1e9f;
      if (row >= 0){
        const uint4* kp = (const uint4*)(krot + (size_t)row * 256 + h * 32);
        uint4 A0 = kp[0], A1 = kp[1], A2 = kp[2], A3 = kp[3];
        unsigned uu[16];
        uu[0]=A0.x; uu[1]=A0.y; uu[2]=A0.z; uu[3]=A0.w;
        uu[4]=A1.x; uu[5]=A1.y; uu[6]=A1.z; uu[7]=A1.w;
        uu[8]=A2.x; uu[9]=A2.y; uu[10]=A2.z; uu[11]=A2.w;
        uu[12]=A3.x; uu[13]=A3.y; uu[14]=A3.z; uu[15]=A3.w;
        // 4 independent partial sums -> dependent-FMA chain 8 deep, not 32
        float s0 = 0.f, s1 = 0.f, s2 = 0.f, s3 = 0.f;
        #pragma unroll
        for (int j = 0; j < 4; ++j){
          s0 += qreg[2*j]      * bflo(uu[j])      + qreg[2*j+1]  * bfhi(uu[j]);
          s1 += qreg[2*j+8]    * bflo(uu[j+4])    + qreg[2*j+9]  * bfhi(uu[j+4]);
          s2 += qreg[2*j+16]   * bflo(uu[j+8])    + qreg[2*j+17] * bfhi(uu[j+8]);
          s3 += qreg[2*j+24]   * bflo(uu[j+12])   + qreg[2*j+25] * bfhi(uu[j+12]);
        }
        lg = (s0 + s1) + (s2 + s3);
      }
      sh_lg[w][kk][h] = lg;
    }
  }

  // softmax: 8 lanes per head (xor 8/16/32 butterflies preserve h)
  float mx = -1e30f;
  for (int kk = ksub; kk < 164; kk += 8) mx = fmaxf(mx, sh_lg[w][kk][h]);
  #pragma unroll
  for (int o = 8; o < 64; o <<= 1) mx = fmaxf(mx, __shfl_xor(mx, o));
  float ssum = 0.f;
  for (int kk = ksub; kk < 164; kk += 8){
    float e = __expf(sh_lg[w][kk][h] - mx);    // invalid keys -> exactly 0
    sh_lg[w][kk][h] = e;
    ssum += e;
  }
  #pragma unroll
  for (int o = 8; o < 64; o <<= 1) ssum += __shfl_xor(ssum, o);
  if (ksub == 0) sh_inv[w][h] = 1.0f / ssum;

  // PV: 2 keys/iter; lane = (parity, 8-dim group); 16B coalesced V loads
  const int c = lane & 31;        // dims c*8 .. c*8+7
  const int p2 = lane >> 5;       // key parity
  const int hh = c >> 2;          // head of this dim group
  float a[8] = {0.f,0.f,0.f,0.f,0.f,0.f,0.f,0.f};
  #pragma unroll 4
  for (int ii = 0; ii < 82; ++ii){
    int kk = ii * 2 + p2;
    int row = sh_row[w][kk];
    int rc = row < 0 ? 0 : row;
    uint4 vv = *(const uint4*)(vmap + (size_t)rc * 256 + c * 8);
    float e = sh_lg[w][kk][hh];   // invalid -> 0
    a[0] += e * bflo(vv.x); a[1] += e * bfhi(vv.x);
    a[2] += e * bflo(vv.y); a[3] += e * bfhi(vv.y);
    a[4] += e * bflo(vv.z); a[5] += e * bfhi(vv.z);
    a[6] += e * bflo(vv.w); a[7] += e * bfhi(vv.w);
  }
  #pragma unroll
  for (int j = 0; j < 8; ++j) a[j] += __shfl_xor(a[j], 32);
  if (p2 == 0){
    float inv = sh_inv[w][hh];
    uint4 o = { pk2bf(a[0]*inv, a[1]*inv), pk2bf(a[2]*inv, a[3]*inv),
                pk2bf(a[4]*inv, a[5]*inv), pk2bf(a[6]*inv, a[7]*inv) };
    *(uint4*)(ao + (size_t)qi * 256 + c * 8) = o;
  }
}

extern "C" void kernel_launch(void* const* d_in, const int* in_sizes, int n_in,
                              void* d_out, int out_size, void* d_ws, size_t ws_size,
                              hipStream_t stream) {
  (void)n_in; (void)out_size; (void)ws_size;
  const float* query  = (const float*)d_in[0];
  const float* qsp    = (const float*)d_in[1];
  const float* fm     = (const float*)d_in[2];
  const float* norm_w = (const float*)d_in[3];
  const float* norm_b = (const float*)d_in[4];
  const float* q_w    = (const float*)d_in[5];
  const float* k_w    = (const float*)d_in[6];
  const float* v_w    = (const float*)d_in[7];
  const float* out_w  = (const float*)d_in[8];
  const float* rope   = (const float*)d_in[9];
  const int*   qbo    = (const int*)d_in[10];
  float* out = (float*)d_out;
  const int n_q = in_sizes[0] / 256;
  const int nbo = in_sizes[10];

  char* p = (char*)d_ws;
  u16* krot = (u16*)p;                       p += (size_t)TOT_ROWS * 256 * 2;
  u16* vmap = (u16*)p;                       p += (size_t)TOT_ROWS * 256 * 2;
  float* qraw = (float*)p;                   p += (size_t)n_q * 256 * 4;
  u16* xbf = (u16*)p;                        p += (size_t)n_q * 256 * 2;
  u16* wtq = (u16*)p;                        p += 65536 * 2;
  u16* wtk = (u16*)p;                        p += 65536 * 2;
  u16* wtv = (u16*)p;                        p += 65536 * 2;
  u16* wto = (u16*)p;
  u16* ao = xbf;   // lifetimes disjoint

  hipLaunchKernelGGL(prep_kernel, dim3(128 + n_q / 4), dim3(256), 0, stream,
                     q_w, k_w, v_w, out_w, query, norm_w, norm_b,
                     wtq, wtk, wtv, wto, xbf);
  hipLaunchKernelGGL(kv_qproj, dim3(KV_BLOCKS + n_q / 16), dim3(512), 0, stream,
                     fm, wtk, wtv, wtq, xbf, rope, krot, vmap, qraw);
  hipLaunchKernelGGL(attn3, dim3(n_q / 4), dim3(256), 0, stream,
                     qraw, qsp, rope, qbo, nbo, krot, vmap, ao);
  hipLaunchKernelGGL(gemm_xw, dim3(n_q / 16, 4), dim3(256), 0, stream,
                     ao, wto, query, out);
}